// Round 3
// baseline (342.928 us; speedup 1.0000x reference)
//
#include <hip/hip_runtime.h>
#include <hip/hip_bf16.h>
#include <cstdint>

// Problem constants
#define SEQ   2048
#define DMOD  1024
#define QKVD  2048
#define NH    16
#define HDIM  128
#define NTOK  4096   // B*S

typedef __bf16 bf16;
typedef bf16 bf16x4 __attribute__((ext_vector_type(4)));
typedef bf16 bf16x8 __attribute__((ext_vector_type(8)));
typedef float f32x4 __attribute__((ext_vector_type(4)));

typedef __attribute__((address_space(1))) void* as1_t;
typedef __attribute__((address_space(3))) void* as3_t;

__device__ __forceinline__ void gload16(const void* g, void* l) {
  __builtin_amdgcn_global_load_lds((as1_t)(uintptr_t)g, (as3_t)(uintptr_t)l, 16, 0, 0);
}

// ---------------- fp32 -> bf16 cast ----------------
__global__ void cast_f32_bf16(const float* __restrict__ in, bf16* __restrict__ out, int n4) {
  int i = blockIdx.x * blockDim.x + threadIdx.x;
  if (i < n4) {
    float4 v = reinterpret_cast<const float4*>(in)[i];
    bf16x4 o;
    o[0] = (bf16)v.x; o[1] = (bf16)v.y; o[2] = (bf16)v.z; o[3] = (bf16)v.w;
    reinterpret_cast<bf16x4*>(out)[i] = o;
  }
}

// ---------------- GEMM: C[M,N] = A[M,K] @ B[N,K]^T ----------------
// mode 0: bf16 out (scaled by oscale), row-major [M,N]
// mode 1: bf16 out, V-transposed: out[(b*2048 + col)*2048 + s]
// mode 2: fp32 out, row-major [M,N]
#define BM 128
#define BN 128
#define BK 64

__global__ __launch_bounds__(256, 2) void gemm_bt_kernel(
    const bf16* __restrict__ A, const bf16* __restrict__ Bw,
    void* __restrict__ Cout, int M, int N, int K, int mode, float oscale)
{
  __shared__ bf16 As[BM * BK];
  __shared__ bf16 Bs[BN * BK];

  const int tid  = threadIdx.x;
  const int lane = tid & 63;
  const int wid  = tid >> 6;
  const int wr   = wid >> 1;
  const int wc   = wid & 1;
  const int lm   = lane & 15;
  const int lg   = lane >> 4;
  const int m0   = blockIdx.y * BM;
  const int n0   = blockIdx.x * BN;

  f32x4 acc[4][4];
#pragma unroll
  for (int i = 0; i < 4; ++i)
#pragma unroll
    for (int j = 0; j < 4; ++j) acc[i][j] = (f32x4)0.0f;

  const int nk = K / BK;

  auto stage = [&](int kt) {
    const int k0 = kt * BK;
    const int rlo = lane >> 3;
    const int cs  = (lane & 7) * 8;
#pragma unroll
    for (int it = 0; it < 4; ++it) {
      int chunk = wid * 4 + it;
      int row = chunk * 8 + rlo;
      gload16(A  + (size_t)(m0 + row) * K + k0 + cs, As + chunk * 512);
      gload16(Bw + (size_t)(n0 + row) * K + k0 + cs, Bs + chunk * 512);
    }
  };

  stage(0);
  __syncthreads();

  for (int kt = 0; kt < nk; ++kt) {
#pragma unroll
    for (int kk = 0; kk < 2; ++kk) {
      bf16x8 a[4], b[4];
#pragma unroll
      for (int mi = 0; mi < 4; ++mi)
        a[mi] = *reinterpret_cast<const bf16x8*>(As + (wr * 64 + mi * 16 + lm) * BK + kk * 32 + lg * 8);
#pragma unroll
      for (int ni = 0; ni < 4; ++ni)
        b[ni] = *reinterpret_cast<const bf16x8*>(Bs + (wc * 64 + ni * 16 + lm) * BK + kk * 32 + lg * 8);
#pragma unroll
      for (int mi = 0; mi < 4; ++mi)
#pragma unroll
        for (int ni = 0; ni < 4; ++ni)
          acc[mi][ni] = __builtin_amdgcn_mfma_f32_16x16x32_bf16(a[mi], b[ni], acc[mi][ni], 0, 0, 0);
    }
    __syncthreads();
    if (kt + 1 < nk) stage(kt + 1);
    __syncthreads();
  }

#pragma unroll
  for (int mi = 0; mi < 4; ++mi) {
#pragma unroll
    for (int ni = 0; ni < 4; ++ni) {
      int col  = n0 + wc * 64 + ni * 16 + lm;
      int row0 = m0 + wr * 64 + mi * 16 + lg * 4;
      f32x4 c = acc[mi][ni];
      if (mode == 0) {
        bf16* Cb = (bf16*)Cout;
#pragma unroll
        for (int r = 0; r < 4; ++r) Cb[(size_t)(row0 + r) * N + col] = (bf16)(c[r] * oscale);
      } else if (mode == 1) {
        bf16* Cb = (bf16*)Cout;
#pragma unroll
        for (int r = 0; r < 4; ++r) {
          int tok = row0 + r; int bb = tok >> 11; int s = tok & 2047;
          Cb[((size_t)bb * QKVD + col) * SEQ + s] = (bf16)c[r];
        }
      } else {
        float* Cf = (float*)Cout;
#pragma unroll
        for (int r = 0; r < 4; ++r) Cf[(size_t)(row0 + r) * N + col] = c[r];
      }
    }
  }
}

// ---------------- Flash attention (causal), parity-split + tile-paired ----------------
// Uniform work: block (pair p, parity q) handles tile p (units j==q mod 2, p+1 of them)
// then tile 15-p (units j==q mod 2, 16-p of them) = 17 units of 64 keys, all blocks equal.
// Each 128-row tile gets 2 partials (even/odd keys), merged by merge_kernel.
// Q pre-scaled by SCALE*log2(e) in the Q GEMM. Defer-max (THR=8) skips O-rescale.
__global__ __launch_bounds__(256, 2) void flash_kernel(
    const bf16* __restrict__ Q, const bf16* __restrict__ Kg,
    const bf16* __restrict__ Vt, bf16* __restrict__ Po, float2* __restrict__ Pml)
{
  __shared__ bf16 KV[2][16384];      // per buf: K 64x128 (8192) | Vt 128x64 (8192) = 32KB
  __shared__ bf16 Pl[4][2][1024];    // per wave, per m-frag: 16 rows x 64 keys, swizzled

  const int tid  = threadIdx.x;
  const int lane = tid & 63;
  const int wid  = tid >> 6;
  const int lm   = lane & 15;
  const int lg   = lane >> 4;

  // XCD-aware decode: xcd = id&7 gets 4 consecutive bh (K+V = 4MB = one L2)
  const int id   = blockIdx.x;               // 0..511
  const int bh   = (id & 7) * 4 + ((id >> 3) & 3);
  const int xx   = id >> 5;                  // 0..15
  const int pr   = xx >> 1;                  // pair index 0..7
  const int qpar = xx & 1;                   // parity 0/1
  const int b    = bh >> 4;
  const int h    = bh & 15;

  auto stage = [&](int j, int buf) {
    bf16* kb = &KV[buf][0];
    bf16* vb = &KV[buf][8192];
    const int rb0 = wid * 16;
#pragma unroll
    for (int i = 0; i < 4; ++i) {
      int r0 = rb0 + i * 4;
      int r  = r0 + (lane >> 4);
      int c  = ((lane & 15) * 16) ^ ((r & 7) << 4);
      gload16(Kg + ((size_t)(b * SEQ + j * 64 + r)) * QKVD + h * HDIM + (c >> 1),
              kb + r0 * 128);
    }
    const int db0 = wid * 32;
#pragma unroll
    for (int i = 0; i < 4; ++i) {
      int d0 = db0 + i * 8;
      int d  = d0 + (lane >> 3);
      int c  = ((lane & 7) * 16) ^ ((d & 7) << 4);
      gload16(Vt + ((size_t)(bh * HDIM + d)) * SEQ + j * 64 + (c >> 1),
              vb + d0 * 64);
    }
  };

  for (int sub = 0; sub < 2; ++sub) {
    const int T  = sub ? (15 - pr) : pr;     // tile index 0..15
    const int nu = T + 1;                    // units for this parity
    const int rA = T * 128 + wid * 16;       // absolute q-row of m-frag 0
    const int rB = rA + 64;

    // Q fragments (pre-scaled by SCALE*log2e)
    bf16x8 qf[2][4];
#pragma unroll
    for (int m = 0; m < 2; ++m) {
      const bf16* qb = Q + ((size_t)(b * SEQ + rA + m * 64 + lm)) * QKVD + h * HDIM + lg * 8;
#pragma unroll
      for (int s4 = 0; s4 < 4; ++s4) qf[m][s4] = *reinterpret_cast<const bf16x8*>(qb + s4 * 32);
    }

    f32x4 o[2][8];
#pragma unroll
    for (int m = 0; m < 2; ++m)
#pragma unroll
      for (int i = 0; i < 8; ++i) o[m][i] = (f32x4)0.0f;
    float mrow[2][4], lrow[2][4];
#pragma unroll
    for (int m = 0; m < 2; ++m)
#pragma unroll
      for (int r = 0; r < 4; ++r) { mrow[m][r] = -__builtin_inff(); lrow[m][r] = 0.0f; }

    stage(qpar, 0);
    __syncthreads();

    int cur = 0;
    for (int i = 0; i < nu; ++i) {
      const int j = qpar + 2 * i;            // k-unit index (64 keys)
      if (i + 1 < nu) stage(qpar + 2 * (i + 1), cur ^ 1);

      const char* kbb = (const char*)&KV[cur][0];
      const char* vbb = kbb + 16384;
      const bool act0 = j * 64 <= rA + 15;
      const bool act1 = j * 64 <= rB + 15;

      // ---- QK^T ----
      f32x4 sa[2][4];
#pragma unroll
      for (int m = 0; m < 2; ++m)
#pragma unroll
        for (int nf = 0; nf < 4; ++nf) sa[m][nf] = (f32x4)0.0f;

#pragma unroll
      for (int nf = 0; nf < 4; ++nf) {
        const int jj = nf * 16 + lm;
        const char* krow = kbb + jj * 256;
        const int jx = (jj & 7) << 4;
        bf16x8 kf[4];
#pragma unroll
        for (int s4 = 0; s4 < 4; ++s4)
          kf[s4] = *(const bf16x8*)(krow + ((s4 * 64 + lg * 16) ^ jx));
        if (act0) {
#pragma unroll
          for (int s4 = 0; s4 < 4; ++s4)
            sa[0][nf] = __builtin_amdgcn_mfma_f32_16x16x32_bf16(qf[0][s4], kf[s4], sa[0][nf], 0, 0, 0);
        }
        if (act1) {
#pragma unroll
          for (int s4 = 0; s4 < 4; ++s4)
            sa[1][nf] = __builtin_amdgcn_mfma_f32_16x16x32_bf16(qf[1][s4], kf[s4], sa[1][nf], 0, 0, 0);
        }
      }

      // ---- online softmax (scores already in log2 domain) ----
#pragma unroll
      for (int m = 0; m < 2; ++m) {
        if (!(m ? act1 : act0)) continue;
        const int rf = rA + m * 64;
        const bool full = (j * 64 + 63) <= rf;
        float t[4][4];
#pragma unroll
        for (int nf = 0; nf < 4; ++nf)
#pragma unroll
          for (int r = 0; r < 4; ++r) {
            float v = sa[m][nf][r];
            if (!full) {
              int key = j * 64 + nf * 16 + lm;
              if (key > rf + lg * 4 + r) v = -1e30f;
            }
            t[nf][r] = v;
          }
        float mx[4];
#pragma unroll
        for (int r = 0; r < 4; ++r)
          mx[r] = fmaxf(fmaxf(t[0][r], t[1][r]), fmaxf(t[2][r], t[3][r]));
#pragma unroll
        for (int d = 1; d < 16; d <<= 1)
#pragma unroll
          for (int r = 0; r < 4; ++r) mx[r] = fmaxf(mx[r], __shfl_xor(mx[r], d));

        int dfl = 1;
#pragma unroll
        for (int r = 0; r < 4; ++r) dfl &= (mx[r] <= mrow[m][r] + 8.0f) ? 1 : 0;
        const bool defer = __all(dfl);

        float p[4][4], rs[4];
        if (defer) {
          // keep old max; P bounded by 2^8, no O-rescale
#pragma unroll
          for (int r = 0; r < 4; ++r) {
            float mn = mrow[m][r];
#pragma unroll
            for (int nf = 0; nf < 4; ++nf) p[nf][r] = exp2f(t[nf][r] - mn);
            rs[r] = (p[0][r] + p[1][r]) + (p[2][r] + p[3][r]);
          }
        } else {
#pragma unroll
          for (int r = 0; r < 4; ++r) {
            float mn = fmaxf(mrow[m][r], mx[r]);
            float scl = exp2f(mrow[m][r] - mn);
            mrow[m][r] = mn;
#pragma unroll
            for (int nf = 0; nf < 4; ++nf) p[nf][r] = exp2f(t[nf][r] - mn);
            rs[r] = (p[0][r] + p[1][r]) + (p[2][r] + p[3][r]);
            lrow[m][r] *= scl;
#pragma unroll
            for (int ni = 0; ni < 8; ++ni) o[m][ni][r] *= scl;
          }
        }
#pragma unroll
        for (int d = 1; d < 16; d <<= 1)
#pragma unroll
          for (int r = 0; r < 4; ++r) rs[r] += __shfl_xor(rs[r], d);
#pragma unroll
        for (int r = 0; r < 4; ++r) lrow[m][r] += rs[r];

        char* pb = (char*)&Pl[wid][m][0];
#pragma unroll
        for (int nf = 0; nf < 4; ++nf)
#pragma unroll
          for (int r = 0; r < 4; ++r) {
            int row = lg * 4 + r;
            *(bf16*)(pb + row * 128 + ((nf * 32 + lm * 2) ^ ((row & 7) << 4))) = (bf16)p[nf][r];
          }
      }

      // ---- PV ----
#pragma unroll
      for (int kk = 0; kk < 2; ++kk) {
        bf16x8 pa[2];
        if (act0) pa[0] = *(const bf16x8*)((const char*)&Pl[wid][0][0] + lm * 128 + ((kk * 64 + lg * 16) ^ ((lm & 7) << 4)));
        if (act1) pa[1] = *(const bf16x8*)((const char*)&Pl[wid][1][0] + lm * 128 + ((kk * 64 + lg * 16) ^ ((lm & 7) << 4)));
#pragma unroll
        for (int ni = 0; ni < 8; ++ni) {
          const int d = ni * 16 + lm;
          bf16x8 vf = *(const bf16x8*)(vbb + d * 128 + ((kk * 64 + lg * 16) ^ ((d & 7) << 4)));
          if (act0) o[0][ni] = __builtin_amdgcn_mfma_f32_16x16x32_bf16(pa[0], vf, o[0][ni], 0, 0, 0);
          if (act1) o[1][ni] = __builtin_amdgcn_mfma_f32_16x16x32_bf16(pa[1], vf, o[1][ni], 0, 0, 0);
        }
      }

      __syncthreads();
      cur ^= 1;
    }

    // ---- partial epilogue: unnormalized o (bf16) + (m, l) per row ----
    const int part = (bh * 16 + T) * 2 + qpar;
#pragma unroll
    for (int m = 0; m < 2; ++m) {
      const int lr0 = wid * 16 + m * 64 + lg * 4;
#pragma unroll
      for (int ni = 0; ni < 8; ++ni)
#pragma unroll
        for (int r = 0; r < 4; ++r)
          Po[((size_t)part * 128 + lr0 + r) * 128 + ni * 16 + lm] = (bf16)o[m][ni][r];
      if (lm == 0) {
#pragma unroll
        for (int r = 0; r < 4; ++r)
          Pml[part * 128 + lr0 + r] = make_float2(mrow[m][r], lrow[m][r]);
      }
    }
  }
}

// ---------------- merge the two parity partials per (bh, tile) ----------------
__global__ void merge_kernel(const bf16* __restrict__ Po, const float2* __restrict__ Pml,
                             bf16* __restrict__ Ob)
{
  const int id  = blockIdx.x;          // bh*16 + t
  const int bh  = id >> 4;
  const int t   = id & 15;
  const int tid = threadIdx.x;         // 256
  const int row = tid >> 1;
  const int dh  = (tid & 1) * 64;
  const int p0  = id * 2, p1 = id * 2 + 1;

  float2 ml0 = Pml[p0 * 128 + row];
  float2 ml1 = Pml[p1 * 128 + row];
  float M  = fmaxf(ml0.x, ml1.x);
  float w0 = exp2f(ml0.x - M);
  float w1 = exp2f(ml1.x - M);
  float inv = 1.0f / (ml0.y * w0 + ml1.y * w1);
  w0 *= inv; w1 *= inv;

  const bf16* o0 = Po + ((size_t)p0 * 128 + row) * 128 + dh;
  const bf16* o1 = Po + ((size_t)p1 * 128 + row) * 128 + dh;
  const int b = bh >> 4, h = bh & 15;
  bf16* out = Ob + ((size_t)(b * SEQ + t * 128 + row)) * QKVD + h * HDIM + dh;

#pragma unroll
  for (int v = 0; v < 8; ++v) {
    bf16x8 a = reinterpret_cast<const bf16x8*>(o0)[v];
    bf16x8 c = reinterpret_cast<const bf16x8*>(o1)[v];
    bf16x8 w;
#pragma unroll
    for (int k = 0; k < 8; ++k) w[k] = (bf16)((float)a[k] * w0 + (float)c[k] * w1);
    reinterpret_cast<bf16x8*>(out)[v] = w;
  }
}

// ---------------- launch ----------------
extern "C" void kernel_launch(void* const* d_in, const int* in_sizes, int n_in,
                              void* d_out, int out_size, void* d_ws, size_t ws_size,
                              hipStream_t stream) {
  const float* x  = (const float*)d_in[0];
  const float* wq = (const float*)d_in[1];
  const float* wk = (const float*)d_in[2];
  const float* wv = (const float*)d_in[3];
  const float* wo = (const float*)d_in[4];
  float* out = (float*)d_out;

  bf16* xb  = (bf16*)d_ws;                 // 4096x1024
  bf16* wqb = xb  + (size_t)NTOK * DMOD;   // 2048x1024
  bf16* wkb = wqb + (size_t)QKVD * DMOD;
  bf16* wvb = wkb + (size_t)QKVD * DMOD;
  bf16* wob = wvb + (size_t)QKVD * DMOD;   // 1024x2048
  bf16* Qb  = wob + (size_t)DMOD * QKVD;   // 4096x2048
  bf16* Kb  = Qb  + (size_t)NTOK * QKVD;
  bf16* Vtb = Kb  + (size_t)NTOK * QKVD;
  bf16* Ob  = Vtb + (size_t)NTOK * QKVD;
  bf16* Po  = Ob  + (size_t)NTOK * QKVD;   // 1024 x 128 x 128 bf16 partials (33.5MB)
  float2* Pml = (float2*)(Po + (size_t)1024 * 128 * 128);  // 1024 x 128 float2 (1MB)

  // casts
  cast_f32_bf16<<<(NTOK * DMOD / 4) / 256, 256, 0, stream>>>(x,  xb,  NTOK * DMOD / 4);
  cast_f32_bf16<<<(QKVD * DMOD / 4) / 256, 256, 0, stream>>>(wq, wqb, QKVD * DMOD / 4);
  cast_f32_bf16<<<(QKVD * DMOD / 4) / 256, 256, 0, stream>>>(wk, wkb, QKVD * DMOD / 4);
  cast_f32_bf16<<<(QKVD * DMOD / 4) / 256, 256, 0, stream>>>(wv, wvb, QKVD * DMOD / 4);
  cast_f32_bf16<<<(DMOD * QKVD / 4) / 256, 256, 0, stream>>>(wo, wob, DMOD * QKVD / 4);

  // QKV projections: [4096,1024] @ [2048,1024]^T -> [4096,2048]
  const float qs = 0.08838834764831845f * 1.4426950408889634f;  // SCALE * log2(e)
  dim3 gqkv(QKVD / BN, NTOK / BM);
  gemm_bt_kernel<<<gqkv, 256, 0, stream>>>(xb, wqb, Qb,  NTOK, QKVD, DMOD, 0, qs);
  gemm_bt_kernel<<<gqkv, 256, 0, stream>>>(xb, wkb, Kb,  NTOK, QKVD, DMOD, 0, 1.0f);
  gemm_bt_kernel<<<gqkv, 256, 0, stream>>>(xb, wvb, Vtb, NTOK, QKVD, DMOD, 1, 1.0f);

  // attention: 512 uniform blocks + merge
  flash_kernel<<<512, 256, 0, stream>>>(Qb, Kb, Vtb, Po, Pml);
  merge_kernel<<<512, 256, 0, stream>>>(Po, Pml, Ob);

  // output projection: [4096,2048] @ [1024,2048]^T -> [4096,1024] fp32
  dim3 gout(DMOD / BN, NTOK / BM);
  gemm_bt_kernel<<<gout, 256, 0, stream>>>(Ob, wob, out, NTOK, DMOD, QKVD, 2, 1.0f);
}

// Round 4
// 229.071 us; speedup vs baseline: 1.4970x; 1.4970x over previous
//
#include <hip/hip_runtime.h>
#include <hip/hip_bf16.h>
#include <cstdint>

// Problem constants
#define SEQ   2048
#define DMOD  1024
#define QKVD  2048
#define NH    16
#define HDIM  128
#define NTOK  4096   // B*S

typedef __bf16 bf16;
typedef bf16 bf16x4 __attribute__((ext_vector_type(4)));
typedef bf16 bf16x8 __attribute__((ext_vector_type(8)));
typedef float f32x4 __attribute__((ext_vector_type(4)));
typedef float f32x16 __attribute__((ext_vector_type(16)));
typedef uint32_t u32x4 __attribute__((ext_vector_type(4)));

typedef __attribute__((address_space(1))) void* as1_t;
typedef __attribute__((address_space(3))) void* as3_t;

__device__ __forceinline__ void gload16(const void* g, void* l) {
  __builtin_amdgcn_global_load_lds((as1_t)(uintptr_t)g, (as3_t)(uintptr_t)l, 16, 0, 0);
}

// pack two f32 -> one u32 of 2 bf16 (compiler emits cvt_pk / cvt+pack)
__device__ __forceinline__ uint32_t pkbf(float a, float b) {
  union { bf16 h; unsigned short u; } x, y;
  x.h = (bf16)a; y.h = (bf16)b;
  return (uint32_t)x.u | ((uint32_t)y.u << 16);
}

// v_permlane32_swap_b32: a.lanes[32:63] <-> b.lanes[0:31]
__device__ __forceinline__ void plswap(uint32_t& a, uint32_t& b) {
  asm("v_permlane32_swap_b32 %0, %1" : "+v"(a), "+v"(b));
}

// ---------------- fp32 -> bf16 cast ----------------
__global__ void cast_f32_bf16(const float* __restrict__ in, bf16* __restrict__ out, int n4) {
  int i = blockIdx.x * blockDim.x + threadIdx.x;
  if (i < n4) {
    float4 v = reinterpret_cast<const float4*>(in)[i];
    bf16x4 o;
    o[0] = (bf16)v.x; o[1] = (bf16)v.y; o[2] = (bf16)v.z; o[3] = (bf16)v.w;
    reinterpret_cast<bf16x4*>(out)[i] = o;
  }
}

// ---------------- GEMM: C[M,N] = A[M,K] @ B[N,K]^T ----------------
#define BM 128
#define BN 128
#define BK 64

__global__ __launch_bounds__(256, 2) void gemm_bt_kernel(
    const bf16* __restrict__ A, const bf16* __restrict__ Bw,
    void* __restrict__ Cout, int M, int N, int K, int mode, float oscale)
{
  __shared__ bf16 As[BM * BK];
  __shared__ bf16 Bs[BN * BK];

  const int tid  = threadIdx.x;
  const int lane = tid & 63;
  const int wid  = tid >> 6;
  const int wr   = wid >> 1;
  const int wc   = wid & 1;
  const int lm   = lane & 15;
  const int lg   = lane >> 4;
  const int m0   = blockIdx.y * BM;
  const int n0   = blockIdx.x * BN;

  f32x4 acc[4][4];
#pragma unroll
  for (int i = 0; i < 4; ++i)
#pragma unroll
    for (int j = 0; j < 4; ++j) acc[i][j] = (f32x4)0.0f;

  const int nk = K / BK;

  auto stage = [&](int kt) {
    const int k0 = kt * BK;
    const int rlo = lane >> 3;
    const int cs  = (lane & 7) * 8;
#pragma unroll
    for (int it = 0; it < 4; ++it) {
      int chunk = wid * 4 + it;
      int row = chunk * 8 + rlo;
      gload16(A  + (size_t)(m0 + row) * K + k0 + cs, As + chunk * 512);
      gload16(Bw + (size_t)(n0 + row) * K + k0 + cs, Bs + chunk * 512);
    }
  };

  stage(0);
  __syncthreads();

  for (int kt = 0; kt < nk; ++kt) {
#pragma unroll
    for (int kk = 0; kk < 2; ++kk) {
      bf16x8 a[4], b[4];
#pragma unroll
      for (int mi = 0; mi < 4; ++mi)
        a[mi] = *reinterpret_cast<const bf16x8*>(As + (wr * 64 + mi * 16 + lm) * BK + kk * 32 + lg * 8);
#pragma unroll
      for (int ni = 0; ni < 4; ++ni)
        b[ni] = *reinterpret_cast<const bf16x8*>(Bs + (wc * 64 + ni * 16 + lm) * BK + kk * 32 + lg * 8);
#pragma unroll
      for (int mi = 0; mi < 4; ++mi)
#pragma unroll
        for (int ni = 0; ni < 4; ++ni)
          acc[mi][ni] = __builtin_amdgcn_mfma_f32_16x16x32_bf16(a[mi], b[ni], acc[mi][ni], 0, 0, 0);
    }
    __syncthreads();
    if (kt + 1 < nk) stage(kt + 1);
    __syncthreads();
  }

#pragma unroll
  for (int mi = 0; mi < 4; ++mi) {
#pragma unroll
    for (int ni = 0; ni < 4; ++ni) {
      int col  = n0 + wc * 64 + ni * 16 + lm;
      int row0 = m0 + wr * 64 + mi * 16 + lg * 4;
      f32x4 c = acc[mi][ni];
      if (mode == 0) {
        bf16* Cb = (bf16*)Cout;
#pragma unroll
        for (int r = 0; r < 4; ++r) Cb[(size_t)(row0 + r) * N + col] = (bf16)(c[r] * oscale);
      } else if (mode == 1) {
        bf16* Cb = (bf16*)Cout;
#pragma unroll
        for (int r = 0; r < 4; ++r) {
          int tok = row0 + r; int bb = tok >> 11; int s = tok & 2047;
          Cb[((size_t)bb * QKVD + col) * SEQ + s] = (bf16)c[r];
        }
      } else {
        float* Cf = (float*)Cout;
#pragma unroll
        for (int r = 0; r < 4; ++r) Cf[(size_t)(row0 + r) * N + col] = c[r];
      }
    }
  }
}

// ---------------- Flash attention: swapped-QK^T 32x32, in-lane softmax ----------------
// Block: 4 waves x 32 q-rows = 128 rows. Parity-split KV units (64 keys), merged later.
// S^T = mfma_32x32x16(A=K, B=Q): lane owns q-row (lane&31); 32 scores in-register
// (keys (r&3)+8*(r>>2)+4*(lane>>5) per kg), other 32 in lane^32.
__global__ __launch_bounds__(256, 2) void flash_kernel(
    const bf16* __restrict__ Q, const bf16* __restrict__ Kg,
    const bf16* __restrict__ Vt, bf16* __restrict__ Po, float2* __restrict__ Pml)
{
  __shared__ bf16 KV[2][16384];      // per buf: K 64x128 (8192) | Vt 128x64 (8192) = 32KB

  const int tid  = threadIdx.x;
  const int lane = tid & 63;
  const int wid  = tid >> 6;
  const int l31  = lane & 31;
  const int lh   = lane >> 5;        // half: 0/1

  // XCD-aware decode: xcd = id&7 gets 4 consecutive bh
  const int id   = blockIdx.x;               // 0..511
  const int bh   = (id & 7) * 4 + ((id >> 3) & 3);
  const int xx   = id >> 5;                  // 0..15
  const int pr   = xx >> 1;                  // pair index 0..7
  const int qpar = xx & 1;                   // parity 0/1
  const int b    = bh >> 4;
  const int h    = bh & 15;

  auto stage = [&](int j, int buf) {
    bf16* kb = &KV[buf][0];
    bf16* vb = &KV[buf][8192];
    const int rb0 = wid * 16;
#pragma unroll
    for (int i = 0; i < 4; ++i) {
      int r0 = rb0 + i * 4;
      int r  = r0 + (lane >> 4);
      int c  = ((lane & 15) * 16) ^ ((r & 7) << 4);
      gload16(Kg + ((size_t)(b * SEQ + j * 64 + r)) * QKVD + h * HDIM + (c >> 1),
              kb + r0 * 128);
    }
    const int db0 = wid * 32;
#pragma unroll
    for (int i = 0; i < 4; ++i) {
      int d0 = db0 + i * 8;
      int d  = d0 + (lane >> 3);
      int c  = ((lane & 7) * 16) ^ ((d & 7) << 4);
      gload16(Vt + ((size_t)(bh * HDIM + d)) * SEQ + j * 64 + (c >> 1),
              vb + d0 * 64);
    }
  };

  for (int sub = 0; sub < 2; ++sub) {
    const int T  = sub ? (15 - pr) : pr;     // tile index 0..15
    const int nu = T + 1;                    // units for this parity
    const int rA = T * 128 + wid * 32;       // wave's q-row base

    // Q fragments as B-operand: lane holds Q[rA + l31][d = lh*8 + step*16 + 0..7]
    bf16x8 qfr[8];
    {
      const bf16* qb = Q + ((size_t)(b * SEQ + rA + l31)) * QKVD + h * HDIM + lh * 8;
#pragma unroll
      for (int st = 0; st < 8; ++st) qfr[st] = *reinterpret_cast<const bf16x8*>(qb + st * 16);
    }

    f32x16 o[4];
#pragma unroll
    for (int c = 0; c < 4; ++c) o[c] = (f32x16)0.0f;
    float mreg = -__builtin_inff();
    float lreg = 0.0f;

    stage(qpar, 0);
    __syncthreads();

    int cur = 0;
    for (int i = 0; i < nu; ++i) {
      const int j = qpar + 2 * i;            // kv-unit (64 keys)
      if (i + 1 < nu) stage(qpar + 2 * (i + 1), cur ^ 1);

      const bool act = (j * 64 <= rA + 31);
      if (act) {
        const char* kbb = (const char*)&KV[cur][0];
        const char* vbb = kbb + 16384;

        // ---- S^T = K Q^T ----
        f32x16 s0 = (f32x16)0.0f, s1 = (f32x16)0.0f;
#pragma unroll
        for (int st = 0; st < 8; ++st) {
          const int r0 = l31, r1 = 32 + l31;
          bf16x8 kf0 = *(const bf16x8*)(kbb + r0 * 256 + ((lh * 16 + st * 32) ^ ((r0 & 7) << 4)));
          bf16x8 kf1 = *(const bf16x8*)(kbb + r1 * 256 + ((lh * 16 + st * 32) ^ ((r1 & 7) << 4)));
          s0 = __builtin_amdgcn_mfma_f32_32x32x16_bf16(kf0, qfr[st], s0, 0, 0, 0);
          s1 = __builtin_amdgcn_mfma_f32_32x32x16_bf16(kf1, qfr[st], s1, 0, 0, 0);
        }

        // ---- causal mask ----
        const bool full = (j * 64 + 63) <= rA;
        if (!full) {
          const int qr  = rA + l31;
          const int kb0 = j * 64 + 4 * lh;
#pragma unroll
          for (int r = 0; r < 16; ++r) {
            int key = kb0 + (r & 3) + 8 * (r >> 2);
            if (key > qr)      s0[r] = -1e30f;
            if (key + 32 > qr) s1[r] = -1e30f;
          }
        }

        // ---- in-lane row stats ----
        float mx = s0[0];
#pragma unroll
        for (int r = 1; r < 16; ++r) mx = fmaxf(mx, s0[r]);
#pragma unroll
        for (int r = 0; r < 16; ++r) mx = fmaxf(mx, s1[r]);
        mx = fmaxf(mx, __shfl_xor(mx, 32));

        float mn;
        if (__all(mx <= mreg + 8.0f)) {
          mn = mreg;                          // defer-max: P bounded by 2^8
        } else {
          mn = fmaxf(mreg, mx);
          float scl = exp2f(mreg - mn);
          mreg = mn;
          lreg *= scl;
#pragma unroll
          for (int r = 0; r < 16; ++r) {      // rescale O: factor per output row
            int row = (r & 3) + 8 * (r >> 2) + 4 * lh;
            float sr = __shfl(scl, row);
#pragma unroll
            for (int c = 0; c < 4; ++c) o[c][r] *= sr;
          }
        }

        // ---- exp + sum ----
        float p[32];
#pragma unroll
        for (int r = 0; r < 16; ++r) p[r]      = exp2f(s0[r] - mn);
#pragma unroll
        for (int r = 0; r < 16; ++r) p[16 + r] = exp2f(s1[r] - mn);
        float rs = 0.0f;
#pragma unroll
        for (int r = 0; r < 32; ++r) rs += p[r];
        rs += __shfl_xor(rs, 32);
        lreg += rs;

        // ---- pack P into PV A-fragments (4 frags of 16 keys) ----
        bf16x8 pa[4];
#pragma unroll
        for (int f = 0; f < 4; ++f) {
          const float* pp = p + f * 8;
          uint32_t w0 = pkbf(pp[0], pp[1]);
          uint32_t w1 = pkbf(pp[2], pp[3]);
          uint32_t w2 = pkbf(pp[4], pp[5]);
          uint32_t w3 = pkbf(pp[6], pp[7]);
          plswap(w0, w2);
          plswap(w1, w3);
          u32x4 w = {w0, w1, w2, w3};
          pa[f] = __builtin_bit_cast(bf16x8, w);
        }

        // ---- O += P V ----
#pragma unroll
        for (int c = 0; c < 4; ++c) {
          const int d = c * 32 + l31;
          const char* vrow = vbb + d * 128;
          const int dx = (d & 7) << 4;
#pragma unroll
          for (int f = 0; f < 4; ++f) {
            bf16x8 vf = *(const bf16x8*)(vrow + ((f * 32 + lh * 16) ^ dx));
            o[c] = __builtin_amdgcn_mfma_f32_32x32x16_bf16(pa[f], vf, o[c], 0, 0, 0);
          }
        }
      }

      __syncthreads();
      cur ^= 1;
    }

    // ---- partial epilogue: unnormalized o (bf16) + (m, l) per row ----
    const int part = (bh * 16 + T) * 2 + qpar;
#pragma unroll
    for (int c = 0; c < 4; ++c)
#pragma unroll
      for (int r = 0; r < 16; ++r) {
        int row = (r & 3) + 8 * (r >> 2) + 4 * lh;
        Po[((size_t)part * 128 + wid * 32 + row) * 128 + c * 32 + l31] = (bf16)o[c][r];
      }
    if (lane < 32)
      Pml[part * 128 + wid * 32 + lane] = make_float2(mreg, lreg);
  }
}

// ---------------- merge the two parity partials per (bh, tile) ----------------
__global__ void merge_kernel(const bf16* __restrict__ Po, const float2* __restrict__ Pml,
                             bf16* __restrict__ Ob)
{
  const int id  = blockIdx.x;          // bh*16 + t
  const int bh  = id >> 4;
  const int t   = id & 15;
  const int tid = threadIdx.x;         // 256
  const int row = tid >> 1;
  const int dh  = (tid & 1) * 64;
  const int p0  = id * 2, p1 = id * 2 + 1;

  float2 ml0 = Pml[p0 * 128 + row];
  float2 ml1 = Pml[p1 * 128 + row];
  float M  = fmaxf(ml0.x, ml1.x);
  float w0 = exp2f(ml0.x - M);
  float w1 = exp2f(ml1.x - M);
  float inv = 1.0f / (ml0.y * w0 + ml1.y * w1);
  w0 *= inv; w1 *= inv;

  const bf16* o0 = Po + ((size_t)p0 * 128 + row) * 128 + dh;
  const bf16* o1 = Po + ((size_t)p1 * 128 + row) * 128 + dh;
  const int b = bh >> 4, h = bh & 15;
  bf16* out = Ob + ((size_t)(b * SEQ + t * 128 + row)) * QKVD + h * HDIM + dh;

#pragma unroll
  for (int v = 0; v < 8; ++v) {
    bf16x8 a = reinterpret_cast<const bf16x8*>(o0)[v];
    bf16x8 c = reinterpret_cast<const bf16x8*>(o1)[v];
    bf16x8 w;
#pragma unroll
    for (int k = 0; k < 8; ++k) w[k] = (bf16)((float)a[k] * w0 + (float)c[k] * w1);
    reinterpret_cast<bf16x8*>(out)[v] = w;
  }
}

// ---------------- launch ----------------
extern "C" void kernel_launch(void* const* d_in, const int* in_sizes, int n_in,
                              void* d_out, int out_size, void* d_ws, size_t ws_size,
                              hipStream_t stream) {
  const float* x  = (const float*)d_in[0];
  const float* wq = (const float*)d_in[1];
  const float* wk = (const float*)d_in[2];
  const float* wv = (const float*)d_in[3];
  const float* wo = (const float*)d_in[4];
  float* out = (float*)d_out;

  bf16* xb  = (bf16*)d_ws;                 // 4096x1024
  bf16* wqb = xb  + (size_t)NTOK * DMOD;   // 2048x1024
  bf16* wkb = wqb + (size_t)QKVD * DMOD;
  bf16* wvb = wkb + (size_t)QKVD * DMOD;
  bf16* wob = wvb + (size_t)QKVD * DMOD;   // 1024x2048
  bf16* Qb  = wob + (size_t)DMOD * QKVD;   // 4096x2048
  bf16* Kb  = Qb  + (size_t)NTOK * QKVD;
  bf16* Vtb = Kb  + (size_t)NTOK * QKVD;
  bf16* Ob  = Vtb + (size_t)NTOK * QKVD;
  bf16* Po  = Ob  + (size_t)NTOK * QKVD;   // 1024 x 128 x 128 bf16 partials
  float2* Pml = (float2*)(Po + (size_t)1024 * 128 * 128);  // 1024 x 128 float2

  // casts
  cast_f32_bf16<<<(NTOK * DMOD / 4) / 256, 256, 0, stream>>>(x,  xb,  NTOK * DMOD / 4);
  cast_f32_bf16<<<(QKVD * DMOD / 4) / 256, 256, 0, stream>>>(wq, wqb, QKVD * DMOD / 4);
  cast_f32_bf16<<<(QKVD * DMOD / 4) / 256, 256, 0, stream>>>(wk, wkb, QKVD * DMOD / 4);
  cast_f32_bf16<<<(QKVD * DMOD / 4) / 256, 256, 0, stream>>>(wv, wvb, QKVD * DMOD / 4);
  cast_f32_bf16<<<(DMOD * QKVD / 4) / 256, 256, 0, stream>>>(wo, wob, DMOD * QKVD / 4);

  // QKV projections: [4096,1024] @ [2048,1024]^T -> [4096,2048]
  const float qs = 0.08838834764831845f * 1.4426950408889634f;  // SCALE * log2(e)
  dim3 gqkv(QKVD / BN, NTOK / BM);
  gemm_bt_kernel<<<gqkv, 256, 0, stream>>>(xb, wqb, Qb,  NTOK, QKVD, DMOD, 0, qs);
  gemm_bt_kernel<<<gqkv, 256, 0, stream>>>(xb, wkb, Kb,  NTOK, QKVD, DMOD, 0, 1.0f);
  gemm_bt_kernel<<<gqkv, 256, 0, stream>>>(xb, wvb, Vtb, NTOK, QKVD, DMOD, 1, 1.0f);

  // attention: 512 uniform blocks + merge
  flash_kernel<<<512, 256, 0, stream>>>(Qb, Kb, Vtb, Po, Pml);
  merge_kernel<<<512, 256, 0, stream>>>(Po, Pml, Ob);

  // output projection: [4096,2048] @ [1024,2048]^T -> [4096,1024] fp32
  dim3 gout(DMOD / BN, NTOK / BM);
  gemm_bt_kernel<<<gout, 256, 0, stream>>>(Ob, wob, out, NTOK, DMOD, QKVD, 2, 1.0f);
}

// Round 5
// 218.978 us; speedup vs baseline: 1.5660x; 1.0461x over previous
//
#include <hip/hip_runtime.h>
#include <hip/hip_bf16.h>
#include <cstdint>

// Problem constants
#define SEQ   2048
#define DMOD  1024
#define QKVD  2048
#define NH    16
#define HDIM  128
#define NTOK  4096   // B*S

typedef __bf16 bf16;
typedef bf16 bf16x4 __attribute__((ext_vector_type(4)));
typedef bf16 bf16x8 __attribute__((ext_vector_type(8)));
typedef float f32x4 __attribute__((ext_vector_type(4)));
typedef float f32x16 __attribute__((ext_vector_type(16)));
typedef uint32_t u32x4 __attribute__((ext_vector_type(4)));

typedef __attribute__((address_space(1))) void* as1_t;
typedef __attribute__((address_space(3))) void* as3_t;

__device__ __forceinline__ void gload16(const void* g, void* l) {
  __builtin_amdgcn_global_load_lds((as1_t)(uintptr_t)g, (as3_t)(uintptr_t)l, 16, 0, 0);
}

// pack two f32 -> one u32 of 2 bf16
__device__ __forceinline__ uint32_t pkbf(float a, float b) {
  union { bf16 h; unsigned short u; } x, y;
  x.h = (bf16)a; y.h = (bf16)b;
  return (uint32_t)x.u | ((uint32_t)y.u << 16);
}

// v_permlane32_swap_b32: a.lanes[32:63] <-> b.lanes[0:31]
__device__ __forceinline__ void plswap(uint32_t& a, uint32_t& b) {
  asm("v_permlane32_swap_b32 %0, %1" : "+v"(a), "+v"(b));
}

// ---------------- fp32 -> bf16 cast ----------------
__global__ void cast_f32_bf16(const float* __restrict__ in, bf16* __restrict__ out, int n4) {
  int i = blockIdx.x * blockDim.x + threadIdx.x;
  if (i < n4) {
    float4 v = reinterpret_cast<const float4*>(in)[i];
    bf16x4 o;
    o[0] = (bf16)v.x; o[1] = (bf16)v.y; o[2] = (bf16)v.z; o[3] = (bf16)v.w;
    reinterpret_cast<bf16x4*>(out)[i] = o;
  }
}

// ---------------- Fused QKV GEMM: 256x256 tile, 8-phase, counted vmcnt ----------------
// C[4096, 6144] = X[4096,1024] @ W[6144,1024]^T, W = [Wq; Wk; Wv] contiguous.
// Epilogue: n<2048 -> Q (scaled); n<4096 -> K; else -> Vt[(b*2048+d)*2048+s].
__global__ __launch_bounds__(512, 1) void qkv_gemm_kernel(
    const bf16* __restrict__ A, const bf16* __restrict__ Bw,
    bf16* __restrict__ Qo, bf16* __restrict__ Ko, bf16* __restrict__ Vto, float qs)
{
  __shared__ bf16 LA[2][256 * 64];   // 32KB each buf
  __shared__ bf16 LB[2][256 * 64];   // 32KB each buf  (total 128KB)

  const int tid  = threadIdx.x;
  const int lane = tid & 63;
  const int wid  = tid >> 6;     // 0..7
  const int wm   = wid >> 2;     // 0..1  (M half)
  const int wn   = wid & 3;      // 0..3  (N quarter)
  const int lm   = lane & 15;
  const int lg   = lane >> 4;

  // bijective XCD swizzle (384 % 8 == 0): chunk of 48 per XCD
  const int bid = (blockIdx.x & 7) * 48 + (blockIdx.x >> 3);
  const int m0  = (bid & 15) * 256;       // 16 m-blocks (consecutive bids share n-panel)
  const int n0  = (bid >> 4) * 256;       // 24 n-blocks

  f32x4 acc[8][4];
#pragma unroll
  for (int i = 0; i < 8; ++i)
#pragma unroll
    for (int j = 0; j < 4; ++j) acc[i][j] = (f32x4)0.0f;

  auto stage = [&](int kt, int buf) {
    const int k0 = kt * 64;
#pragma unroll
    for (int i = 0; i < 4; ++i) {
      int chunk = wid * 4 + i;                 // 0..31, 1KB = 8 rows x 128B
      int row   = chunk * 8 + (lane >> 3);
      int cb    = ((lane & 7) * 16) ^ ((row & 7) << 4);   // inverse-swizzled src
      gload16(A  + (size_t)(m0 + row) * DMOD + k0 + (cb >> 1), &LA[buf][chunk * 512]);
      gload16(Bw + (size_t)(n0 + row) * DMOD + k0 + (cb >> 1), &LB[buf][chunk * 512]);
    }
  };

  auto rdA = [&](int buf, int mf, int kk) -> bf16x8 {
    int row = wm * 128 + mf * 16 + lm;
    int cb  = (kk * 64 + lg * 16) ^ ((row & 7) << 4);
    return *(const bf16x8*)((const char*)&LA[buf][0] + row * 128 + cb);
  };
  auto rdB = [&](int buf, int nf, int kk) -> bf16x8 {
    int row = wn * 64 + nf * 16 + lm;
    int cb  = (kk * 64 + lg * 16) ^ ((row & 7) << 4);
    return *(const bf16x8*)((const char*)&LB[buf][0] + row * 128 + cb);
  };

  stage(0, 0);

  for (int t = 0; t < 16; ++t) {
    const int c = t & 1;
    if (t < 15) {
      stage(t + 1, c ^ 1);                       // issue BEFORE wait: stays in flight
      asm volatile("s_waitcnt vmcnt(8)" ::: "memory");   // tile t landed (FIFO)
    } else {
      asm volatile("s_waitcnt vmcnt(0)" ::: "memory");
    }
    __builtin_amdgcn_s_barrier();                // all waves: buf[c] ready

    bf16x8 a[4][2], b[2][2];

    // ---- phase 0: A m0-3, B n0-1 ----
#pragma unroll
    for (int mf = 0; mf < 4; ++mf)
#pragma unroll
      for (int kk = 0; kk < 2; ++kk) a[mf][kk] = rdA(c, mf, kk);
#pragma unroll
    for (int nf = 0; nf < 2; ++nf)
#pragma unroll
      for (int kk = 0; kk < 2; ++kk) b[nf][kk] = rdB(c, nf, kk);
    __builtin_amdgcn_s_barrier();
    __builtin_amdgcn_s_setprio(1);
#pragma unroll
    for (int mf = 0; mf < 4; ++mf)
#pragma unroll
      for (int nf = 0; nf < 2; ++nf)
#pragma unroll
        for (int kk = 0; kk < 2; ++kk)
          acc[mf][nf] = __builtin_amdgcn_mfma_f32_16x16x32_bf16(a[mf][kk], b[nf][kk], acc[mf][nf], 0, 0, 0);
    __builtin_amdgcn_s_setprio(0);
    __builtin_amdgcn_s_barrier();

    // ---- phase 1: B n2-3 (A m0-3 reused) ----
#pragma unroll
    for (int nf = 0; nf < 2; ++nf)
#pragma unroll
      for (int kk = 0; kk < 2; ++kk) b[nf][kk] = rdB(c, 2 + nf, kk);
    __builtin_amdgcn_s_barrier();
    __builtin_amdgcn_s_setprio(1);
#pragma unroll
    for (int mf = 0; mf < 4; ++mf)
#pragma unroll
      for (int nf = 0; nf < 2; ++nf)
#pragma unroll
        for (int kk = 0; kk < 2; ++kk)
          acc[mf][2 + nf] = __builtin_amdgcn_mfma_f32_16x16x32_bf16(a[mf][kk], b[nf][kk], acc[mf][2 + nf], 0, 0, 0);
    __builtin_amdgcn_s_setprio(0);
    __builtin_amdgcn_s_barrier();

    // ---- phase 2: A m4-7 (B n2-3 reused) ----
#pragma unroll
    for (int mf = 0; mf < 4; ++mf)
#pragma unroll
      for (int kk = 0; kk < 2; ++kk) a[mf][kk] = rdA(c, 4 + mf, kk);
    __builtin_amdgcn_s_barrier();
    __builtin_amdgcn_s_setprio(1);
#pragma unroll
    for (int mf = 0; mf < 4; ++mf)
#pragma unroll
      for (int nf = 0; nf < 2; ++nf)
#pragma unroll
        for (int kk = 0; kk < 2; ++kk)
          acc[4 + mf][2 + nf] = __builtin_amdgcn_mfma_f32_16x16x32_bf16(a[mf][kk], b[nf][kk], acc[4 + mf][2 + nf], 0, 0, 0);
    __builtin_amdgcn_s_setprio(0);
    __builtin_amdgcn_s_barrier();

    // ---- phase 3: B n0-1 again (A m4-7 reused) ----
#pragma unroll
    for (int nf = 0; nf < 2; ++nf)
#pragma unroll
      for (int kk = 0; kk < 2; ++kk) b[nf][kk] = rdB(c, nf, kk);
    __builtin_amdgcn_s_barrier();
    __builtin_amdgcn_s_setprio(1);
#pragma unroll
    for (int mf = 0; mf < 4; ++mf)
#pragma unroll
      for (int nf = 0; nf < 2; ++nf)
#pragma unroll
        for (int kk = 0; kk < 2; ++kk)
          acc[4 + mf][nf] = __builtin_amdgcn_mfma_f32_16x16x32_bf16(a[mf][kk], b[nf][kk], acc[4 + mf][nf], 0, 0, 0);
    __builtin_amdgcn_s_setprio(0);
    __builtin_amdgcn_s_barrier();                // guards buf[c] reuse next iter
  }

  // ---- epilogue ----
#pragma unroll
  for (int mf = 0; mf < 8; ++mf) {
#pragma unroll
    for (int nf = 0; nf < 4; ++nf) {
      int row0 = m0 + wm * 128 + mf * 16 + lg * 4;
      int col  = n0 + wn * 64 + nf * 16 + lm;
      f32x4 cv = acc[mf][nf];
      if (n0 < 2048) {
#pragma unroll
        for (int r = 0; r < 4; ++r)
          Qo[(size_t)(row0 + r) * QKVD + col] = (bf16)(cv[r] * qs);
      } else if (n0 < 4096) {
        int kc = col - 2048;
#pragma unroll
        for (int r = 0; r < 4; ++r)
          Ko[(size_t)(row0 + r) * QKVD + kc] = (bf16)cv[r];
      } else {
        int vc = col - 4096;
#pragma unroll
        for (int r = 0; r < 4; ++r) {
          int tok = row0 + r; int bb = tok >> 11; int s = tok & 2047;
          Vto[((size_t)bb * QKVD + vc) * SEQ + s] = (bf16)cv[r];
        }
      }
    }
  }
}

// ---------------- GEMM: C[M,N] = A[M,K] @ B[N,K]^T (128x128, used for out-proj) ----------------
#define BM 128
#define BN 128
#define BK 64

__global__ __launch_bounds__(256, 2) void gemm_bt_kernel(
    const bf16* __restrict__ A, const bf16* __restrict__ Bw,
    void* __restrict__ Cout, int M, int N, int K, int mode, float oscale)
{
  __shared__ bf16 As[BM * BK];
  __shared__ bf16 Bs[BN * BK];

  const int tid  = threadIdx.x;
  const int lane = tid & 63;
  const int wid  = tid >> 6;
  const int wr   = wid >> 1;
  const int wc   = wid & 1;
  const int lm   = lane & 15;
  const int lg   = lane >> 4;
  const int m0   = blockIdx.y * BM;
  const int n0   = blockIdx.x * BN;

  f32x4 acc[4][4];
#pragma unroll
  for (int i = 0; i < 4; ++i)
#pragma unroll
    for (int j = 0; j < 4; ++j) acc[i][j] = (f32x4)0.0f;

  const int nk = K / BK;

  auto stage = [&](int kt) {
    const int k0 = kt * BK;
    const int rlo = lane >> 3;
    const int cs  = (lane & 7) * 8;
#pragma unroll
    for (int it = 0; it < 4; ++it) {
      int chunk = wid * 4 + it;
      int row = chunk * 8 + rlo;
      gload16(A  + (size_t)(m0 + row) * K + k0 + cs, As + chunk * 512);
      gload16(Bw + (size_t)(n0 + row) * K + k0 + cs, Bs + chunk * 512);
    }
  };

  stage(0);
  __syncthreads();

  for (int kt = 0; kt < nk; ++kt) {
#pragma unroll
    for (int kk = 0; kk < 2; ++kk) {
      bf16x8 a[4], b[4];
#pragma unroll
      for (int mi = 0; mi < 4; ++mi)
        a[mi] = *reinterpret_cast<const bf16x8*>(As + (wr * 64 + mi * 16 + lm) * BK + kk * 32 + lg * 8);
#pragma unroll
      for (int ni = 0; ni < 4; ++ni)
        b[ni] = *reinterpret_cast<const bf16x8*>(Bs + (wc * 64 + ni * 16 + lm) * BK + kk * 32 + lg * 8);
#pragma unroll
      for (int mi = 0; mi < 4; ++mi)
#pragma unroll
        for (int ni = 0; ni < 4; ++ni)
          acc[mi][ni] = __builtin_amdgcn_mfma_f32_16x16x32_bf16(a[mi], b[ni], acc[mi][ni], 0, 0, 0);
    }
    __syncthreads();
    if (kt + 1 < nk) stage(kt + 1);
    __syncthreads();
  }

#pragma unroll
  for (int mi = 0; mi < 4; ++mi) {
#pragma unroll
    for (int ni = 0; ni < 4; ++ni) {
      int col  = n0 + wc * 64 + ni * 16 + lm;
      int row0 = m0 + wr * 64 + mi * 16 + lg * 4;
      f32x4 c = acc[mi][ni];
      if (mode == 0) {
        bf16* Cb = (bf16*)Cout;
#pragma unroll
        for (int r = 0; r < 4; ++r) Cb[(size_t)(row0 + r) * N + col] = (bf16)(c[r] * oscale);
      } else {
        float* Cf = (float*)Cout;
#pragma unroll
        for (int r = 0; r < 4; ++r) Cf[(size_t)(row0 + r) * N + col] = c[r];
      }
    }
  }
}

// ---------------- Flash attention: swapped-QK^T 32x32, in-lane softmax ----------------
__global__ __launch_bounds__(256, 2) void flash_kernel(
    const bf16* __restrict__ Q, const bf16* __restrict__ Kg,
    const bf16* __restrict__ Vt, bf16* __restrict__ Po, float2* __restrict__ Pml)
{
  __shared__ bf16 KV[2][16384];      // per buf: K 64x128 (8192) | Vt 128x64 (8192) = 32KB

  const int tid  = threadIdx.x;
  const int lane = tid & 63;
  const int wid  = tid >> 6;
  const int l31  = lane & 31;
  const int lh   = lane >> 5;        // half: 0/1

  const int id   = blockIdx.x;               // 0..511
  const int bh   = (id & 7) * 4 + ((id >> 3) & 3);
  const int xx   = id >> 5;                  // 0..15
  const int pr   = xx >> 1;                  // pair index 0..7
  const int qpar = xx & 1;                   // parity 0/1
  const int b    = bh >> 4;
  const int h    = bh & 15;

  auto stage = [&](int j, int buf) {
    bf16* kb = &KV[buf][0];
    bf16* vb = &KV[buf][8192];
    const int rb0 = wid * 16;
#pragma unroll
    for (int i = 0; i < 4; ++i) {
      int r0 = rb0 + i * 4;
      int r  = r0 + (lane >> 4);
      int c  = ((lane & 15) * 16) ^ ((r & 7) << 4);
      gload16(Kg + ((size_t)(b * SEQ + j * 64 + r)) * QKVD + h * HDIM + (c >> 1),
              kb + r0 * 128);
    }
    const int db0 = wid * 32;
#pragma unroll
    for (int i = 0; i < 4; ++i) {
      int d0 = db0 + i * 8;
      int d  = d0 + (lane >> 3);
      int c  = ((lane & 7) * 16) ^ ((d & 7) << 4);
      gload16(Vt + ((size_t)(bh * HDIM + d)) * SEQ + j * 64 + (c >> 1),
              vb + d0 * 64);
    }
  };

  for (int sub = 0; sub < 2; ++sub) {
    const int T  = sub ? (15 - pr) : pr;     // tile index 0..15
    const int nu = T + 1;                    // units for this parity
    const int rA = T * 128 + wid * 32;       // wave's q-row base

    bf16x8 qfr[8];
    {
      const bf16* qb = Q + ((size_t)(b * SEQ + rA + l31)) * QKVD + h * HDIM + lh * 8;
#pragma unroll
      for (int st = 0; st < 8; ++st) qfr[st] = *reinterpret_cast<const bf16x8*>(qb + st * 16);
    }

    f32x16 o[4];
#pragma unroll
    for (int c = 0; c < 4; ++c) o[c] = (f32x16)0.0f;
    float mreg = -__builtin_inff();
    float lreg = 0.0f;

    stage(qpar, 0);
    __syncthreads();

    int cur = 0;
    for (int i = 0; i < nu; ++i) {
      const int j = qpar + 2 * i;            // kv-unit (64 keys)
      if (i + 1 < nu) stage(qpar + 2 * (i + 1), cur ^ 1);

      const bool act = (j * 64 <= rA + 31);
      if (act) {
        const char* kbb = (const char*)&KV[cur][0];
        const char* vbb = kbb + 16384;

        // ---- S^T = K Q^T ----
        f32x16 s0 = (f32x16)0.0f, s1 = (f32x16)0.0f;
#pragma unroll
        for (int st = 0; st < 8; ++st) {
          const int r0 = l31, r1 = 32 + l31;
          bf16x8 kf0 = *(const bf16x8*)(kbb + r0 * 256 + ((lh * 16 + st * 32) ^ ((r0 & 7) << 4)));
          bf16x8 kf1 = *(const bf16x8*)(kbb + r1 * 256 + ((lh * 16 + st * 32) ^ ((r1 & 7) << 4)));
          s0 = __builtin_amdgcn_mfma_f32_32x32x16_bf16(kf0, qfr[st], s0, 0, 0, 0);
          s1 = __builtin_amdgcn_mfma_f32_32x32x16_bf16(kf1, qfr[st], s1, 0, 0, 0);
        }

        // ---- causal mask ----
        const bool full = (j * 64 + 63) <= rA;
        if (!full) {
          const int qr  = rA + l31;
          const int kb0 = j * 64 + 4 * lh;
#pragma unroll
          for (int r = 0; r < 16; ++r) {
            int key = kb0 + (r & 3) + 8 * (r >> 2);
            if (key > qr)      s0[r] = -1e30f;
            if (key + 32 > qr) s1[r] = -1e30f;
          }
        }

        // ---- in-lane row stats ----
        float mx = s0[0];
#pragma unroll
        for (int r = 1; r < 16; ++r) mx = fmaxf(mx, s0[r]);
#pragma unroll
        for (int r = 0; r < 16; ++r) mx = fmaxf(mx, s1[r]);
        mx = fmaxf(mx, __shfl_xor(mx, 32));

        float mn;
        if (__all(mx <= mreg + 8.0f)) {
          mn = mreg;                          // defer-max
        } else {
          mn = fmaxf(mreg, mx);
          float scl = exp2f(mreg - mn);
          mreg = mn;
          lreg *= scl;
#pragma unroll
          for (int r = 0; r < 16; ++r) {
            int row = (r & 3) + 8 * (r >> 2) + 4 * lh;
            float sr = __shfl(scl, row);
#pragma unroll
            for (int c = 0; c < 4; ++c) o[c][r] *= sr;
          }
        }

        // ---- exp + sum ----
        float p[32];
#pragma unroll
        for (int r = 0; r < 16; ++r) p[r]      = exp2f(s0[r] - mn);
#pragma unroll
        for (int r = 0; r < 16; ++r) p[16 + r] = exp2f(s1[r] - mn);
        float rs = 0.0f;
#pragma unroll
        for (int r = 0; r < 32; ++r) rs += p[r];
        rs += __shfl_xor(rs, 32);
        lreg += rs;

        // ---- pack P into PV A-fragments ----
        bf16x8 pa[4];
#pragma unroll
        for (int f = 0; f < 4; ++f) {
          const float* pp = p + f * 8;
          uint32_t w0 = pkbf(pp[0], pp[1]);
          uint32_t w1 = pkbf(pp[2], pp[3]);
          uint32_t w2 = pkbf(pp[4], pp[5]);
          uint32_t w3 = pkbf(pp[6], pp[7]);
          plswap(w0, w2);
          plswap(w1, w3);
          u32x4 w = {w0, w1, w2, w3};
          pa[f] = __builtin_bit_cast(bf16x8, w);
        }

        // ---- O += P V ----
#pragma unroll
        for (int c = 0; c < 4; ++c) {
          const int d = c * 32 + l31;
          const char* vrow = vbb + d * 128;
          const int dx = (d & 7) << 4;
#pragma unroll
          for (int f = 0; f < 4; ++f) {
            bf16x8 vf = *(const bf16x8*)(vrow + ((f * 32 + lh * 16) ^ dx));
            o[c] = __builtin_amdgcn_mfma_f32_32x32x16_bf16(pa[f], vf, o[c], 0, 0, 0);
          }
        }
      }

      __syncthreads();
      cur ^= 1;
    }

    // ---- partial epilogue ----
    const int part = (bh * 16 + T) * 2 + qpar;
#pragma unroll
    for (int c = 0; c < 4; ++c)
#pragma unroll
      for (int r = 0; r < 16; ++r) {
        int row = (r & 3) + 8 * (r >> 2) + 4 * lh;
        Po[((size_t)part * 128 + wid * 32 + row) * 128 + c * 32 + l31] = (bf16)o[c][r];
      }
    if (lane < 32)
      Pml[part * 128 + wid * 32 + lane] = make_float2(mreg, lreg);
  }
}

// ---------------- merge the two parity partials per (bh, tile) ----------------
__global__ void merge_kernel(const bf16* __restrict__ Po, const float2* __restrict__ Pml,
                             bf16* __restrict__ Ob)
{
  const int id  = blockIdx.x;          // bh*16 + t
  const int bh  = id >> 4;
  const int t   = id & 15;
  const int tid = threadIdx.x;         // 256
  const int row = tid >> 1;
  const int dh  = (tid & 1) * 64;
  const int p0  = id * 2, p1 = id * 2 + 1;

  float2 ml0 = Pml[p0 * 128 + row];
  float2 ml1 = Pml[p1 * 128 + row];
  float M  = fmaxf(ml0.x, ml1.x);
  float w0 = exp2f(ml0.x - M);
  float w1 = exp2f(ml1.x - M);
  float inv = 1.0f / (ml0.y * w0 + ml1.y * w1);
  w0 *= inv; w1 *= inv;

  const bf16* o0 = Po + ((size_t)p0 * 128 + row) * 128 + dh;
  const bf16* o1 = Po + ((size_t)p1 * 128 + row) * 128 + dh;
  const int b = bh >> 4, h = bh & 15;
  bf16* out = Ob + ((size_t)(b * SEQ + t * 128 + row)) * QKVD + h * HDIM + dh;

#pragma unroll
  for (int v = 0; v < 8; ++v) {
    bf16x8 a = reinterpret_cast<const bf16x8*>(o0)[v];
    bf16x8 c = reinterpret_cast<const bf16x8*>(o1)[v];
    bf16x8 w;
#pragma unroll
    for (int k = 0; k < 8; ++k) w[k] = (bf16)((float)a[k] * w0 + (float)c[k] * w1);
    reinterpret_cast<bf16x8*>(out)[v] = w;
  }
}

// ---------------- launch ----------------
extern "C" void kernel_launch(void* const* d_in, const int* in_sizes, int n_in,
                              void* d_out, int out_size, void* d_ws, size_t ws_size,
                              hipStream_t stream) {
  const float* x  = (const float*)d_in[0];
  const float* wq = (const float*)d_in[1];
  const float* wk = (const float*)d_in[2];
  const float* wv = (const float*)d_in[3];
  const float* wo = (const float*)d_in[4];
  float* out = (float*)d_out;

  bf16* xb  = (bf16*)d_ws;                 // 4096x1024
  bf16* wqb = xb  + (size_t)NTOK * DMOD;   // 2048x1024 (wq/wk/wv contiguous = fused [6144,1024])
  bf16* wkb = wqb + (size_t)QKVD * DMOD;
  bf16* wvb = wkb + (size_t)QKVD * DMOD;
  bf16* wob = wvb + (size_t)QKVD * DMOD;   // 1024x2048
  bf16* Qb  = wob + (size_t)DMOD * QKVD;   // 4096x2048
  bf16* Kb  = Qb  + (size_t)NTOK * QKVD;
  bf16* Vtb = Kb  + (size_t)NTOK * QKVD;
  bf16* Ob  = Vtb + (size_t)NTOK * QKVD;
  bf16* Po  = Ob  + (size_t)NTOK * QKVD;   // 1024 x 128 x 128 bf16 partials
  float2* Pml = (float2*)(Po + (size_t)1024 * 128 * 128);  // 1024 x 128 float2

  // casts
  cast_f32_bf16<<<(NTOK * DMOD / 4) / 256, 256, 0, stream>>>(x,  xb,  NTOK * DMOD / 4);
  cast_f32_bf16<<<(QKVD * DMOD / 4) / 256, 256, 0, stream>>>(wq, wqb, QKVD * DMOD / 4);
  cast_f32_bf16<<<(QKVD * DMOD / 4) / 256, 256, 0, stream>>>(wk, wkb, QKVD * DMOD / 4);
  cast_f32_bf16<<<(QKVD * DMOD / 4) / 256, 256, 0, stream>>>(wv, wvb, QKVD * DMOD / 4);
  cast_f32_bf16<<<(DMOD * QKVD / 4) / 256, 256, 0, stream>>>(wo, wob, DMOD * QKVD / 4);

  // fused QKV projection: [4096,1024] @ [6144,1024]^T
  const float qs = 0.08838834764831845f * 1.4426950408889634f;  // SCALE * log2(e)
  qkv_gemm_kernel<<<384, 512, 0, stream>>>(xb, wqb, Qb, Kb, Vtb, qs);

  // attention: 512 uniform blocks + merge
  flash_kernel<<<512, 256, 0, stream>>>(Qb, Kb, Vtb, Po, Pml);
  merge_kernel<<<512, 256, 0, stream>>>(Po, Pml, Ob);

  // output projection: [4096,2048] @ [1024,2048]^T -> [4096,1024] fp32
  dim3 gout(DMOD / BN, NTOK / BM);
  gemm_bt_kernel<<<gout, 256, 0, stream>>>(Ob, wob, out, NTOK, DMOD, QKVD, 2, 1.0f);
}

// Round 6
// 190.356 us; speedup vs baseline: 1.8015x; 1.1504x over previous
//
#include <hip/hip_runtime.h>
#include <hip/hip_bf16.h>
#include <cstdint>

// Problem constants
#define SEQ   2048
#define DMOD  1024
#define QKVD  2048
#define NH    16
#define HDIM  128
#define NTOK  4096   // B*S

typedef __bf16 bf16;
typedef bf16 bf16x4 __attribute__((ext_vector_type(4)));
typedef bf16 bf16x8 __attribute__((ext_vector_type(8)));
typedef float f32x4 __attribute__((ext_vector_type(4)));
typedef float f32x16 __attribute__((ext_vector_type(16)));
typedef uint32_t u32x4 __attribute__((ext_vector_type(4)));

typedef __attribute__((address_space(1))) void* as1_t;
typedef __attribute__((address_space(3))) void* as3_t;

__device__ __forceinline__ void gload16(const void* g, void* l) {
  __builtin_amdgcn_global_load_lds((as1_t)(uintptr_t)g, (as3_t)(uintptr_t)l, 16, 0, 0);
}

// pack two f32 -> one u32 of 2 bf16
__device__ __forceinline__ uint32_t pkbf(float a, float b) {
  union { bf16 h; unsigned short u; } x, y;
  x.h = (bf16)a; y.h = (bf16)b;
  return (uint32_t)x.u | ((uint32_t)y.u << 16);
}

// v_permlane32_swap_b32: a.lanes[32:63] <-> b.lanes[0:31]
__device__ __forceinline__ void plswap(uint32_t& a, uint32_t& b) {
  asm("v_permlane32_swap_b32 %0, %1" : "+v"(a), "+v"(b));
}

// ---------------- fp32 -> bf16 cast ----------------
__global__ void cast_f32_bf16(const float* __restrict__ in, bf16* __restrict__ out, int n4) {
  int i = blockIdx.x * blockDim.x + threadIdx.x;
  if (i < n4) {
    float4 v = reinterpret_cast<const float4*>(in)[i];
    bf16x4 o;
    o[0] = (bf16)v.x; o[1] = (bf16)v.y; o[2] = (bf16)v.z; o[3] = (bf16)v.w;
    reinterpret_cast<bf16x4*>(out)[i] = o;
  }
}

// ---------------- Fused QKV GEMM: 128x256 tile, counted vmcnt, grid 768 ----------------
// C[4096, 6144] = X[4096,1024] @ W[6144,1024]^T, W = [Wq; Wk; Wv] contiguous.
// 8 waves: wave grid 2m x 4n, wave tile 64x64. LDS 96KB dbuf. Grid 768 = 3 exact rounds.
__global__ __launch_bounds__(512, 1) void qkv_gemm_kernel(
    const bf16* __restrict__ A, const bf16* __restrict__ Bw,
    bf16* __restrict__ Qo, bf16* __restrict__ Ko, bf16* __restrict__ Vto, float qs)
{
  __shared__ bf16 LA[2][128 * 64];   // 16KB per buf
  __shared__ bf16 LB[2][256 * 64];   // 32KB per buf  (total 96KB)

  const int tid  = threadIdx.x;
  const int lane = tid & 63;
  const int wid  = tid >> 6;     // 0..7
  const int wm   = wid >> 2;     // 0..1  (M half, 64 rows)
  const int wn   = wid & 3;      // 0..3  (N quarter, 64 cols)
  const int lm   = lane & 15;
  const int lg   = lane >> 4;

  // per-XCD chunk: 16 m-blocks x 6 n-panels (bijective, 768 % 8 == 0)
  const int g   = blockIdx.x & 7;
  const int idx = blockIdx.x >> 3;            // 0..95
  const int m0  = ((g & 1) * 16 + (idx & 15)) * 128;
  const int n0  = ((g >> 1) * 6 + (idx >> 4)) * 256;

  f32x4 acc[4][4];
#pragma unroll
  for (int i = 0; i < 4; ++i)
#pragma unroll
    for (int j = 0; j < 4; ++j) acc[i][j] = (f32x4)0.0f;

  auto stage = [&](int kt, int buf) {
    const int k0 = kt * 64;
    const int rl = lane >> 3;                 // 0..7
    const int cb = (lane & 7) * 16;           // byte col base
#pragma unroll
    for (int i = 0; i < 2; ++i) {             // A: 16 chunks, 2/wave
      int chunk = wid * 2 + i;
      int row   = chunk * 8 + rl;
      int cx    = cb ^ ((row & 7) << 4);
      gload16(A + (size_t)(m0 + row) * DMOD + k0 + (cx >> 1), &LA[buf][chunk * 512]);
    }
#pragma unroll
    for (int i = 0; i < 4; ++i) {             // B: 32 chunks, 4/wave
      int chunk = wid * 4 + i;
      int row   = chunk * 8 + rl;
      int cx    = cb ^ ((row & 7) << 4);
      gload16(Bw + (size_t)(n0 + row) * DMOD + k0 + (cx >> 1), &LB[buf][chunk * 512]);
    }
  };

  auto rdA = [&](int buf, int mf, int kk) -> bf16x8 {
    int row = wm * 64 + mf * 16 + lm;
    int cb  = (kk * 64 + lg * 16) ^ ((row & 7) << 4);
    return *(const bf16x8*)((const char*)&LA[buf][0] + row * 128 + cb);
  };
  auto rdB = [&](int buf, int nf, int kk) -> bf16x8 {
    int row = wn * 64 + nf * 16 + lm;
    int cb  = (kk * 64 + lg * 16) ^ ((row & 7) << 4);
    return *(const bf16x8*)((const char*)&LB[buf][0] + row * 128 + cb);
  };

  stage(0, 0);

  for (int t = 0; t < 16; ++t) {
    const int c = t & 1;
    if (t < 15) {
      stage(t + 1, c ^ 1);                    // issue BEFORE wait: stays in flight
      asm volatile("s_waitcnt vmcnt(6)" ::: "memory");   // tile t landed (6 loads/thread)
    } else {
      asm volatile("s_waitcnt vmcnt(0)" ::: "memory");
    }
    __builtin_amdgcn_s_barrier();             // all waves: buf[c] ready

    bf16x8 a[4][2], b[2][2];

    // ---- phase 0: A all, B n0-1 ----
#pragma unroll
    for (int mf = 0; mf < 4; ++mf)
#pragma unroll
      for (int kk = 0; kk < 2; ++kk) a[mf][kk] = rdA(c, mf, kk);
#pragma unroll
    for (int nf = 0; nf < 2; ++nf)
#pragma unroll
      for (int kk = 0; kk < 2; ++kk) b[nf][kk] = rdB(c, nf, kk);
    __builtin_amdgcn_s_barrier();
    __builtin_amdgcn_s_setprio(1);
#pragma unroll
    for (int mf = 0; mf < 4; ++mf)
#pragma unroll
      for (int nf = 0; nf < 2; ++nf)
#pragma unroll
        for (int kk = 0; kk < 2; ++kk)
          acc[mf][nf] = __builtin_amdgcn_mfma_f32_16x16x32_bf16(a[mf][kk], b[nf][kk], acc[mf][nf], 0, 0, 0);
    __builtin_amdgcn_s_setprio(0);
    __builtin_amdgcn_s_barrier();

    // ---- phase 1: B n2-3 (A reused) ----
#pragma unroll
    for (int nf = 0; nf < 2; ++nf)
#pragma unroll
      for (int kk = 0; kk < 2; ++kk) b[nf][kk] = rdB(c, 2 + nf, kk);
    __builtin_amdgcn_s_barrier();
    __builtin_amdgcn_s_setprio(1);
#pragma unroll
    for (int mf = 0; mf < 4; ++mf)
#pragma unroll
      for (int nf = 0; nf < 2; ++nf)
#pragma unroll
        for (int kk = 0; kk < 2; ++kk)
          acc[mf][2 + nf] = __builtin_amdgcn_mfma_f32_16x16x32_bf16(a[mf][kk], b[nf][kk], acc[mf][2 + nf], 0, 0, 0);
    __builtin_amdgcn_s_setprio(0);
    __builtin_amdgcn_s_barrier();             // guards buf[c] reuse next iter
  }

  // ---- epilogue ----
#pragma unroll
  for (int mf = 0; mf < 4; ++mf) {
#pragma unroll
    for (int nf = 0; nf < 4; ++nf) {
      int row0 = m0 + wm * 64 + mf * 16 + lg * 4;
      int col  = n0 + wn * 64 + nf * 16 + lm;
      f32x4 cv = acc[mf][nf];
      if (n0 < 2048) {
#pragma unroll
        for (int r = 0; r < 4; ++r)
          Qo[(size_t)(row0 + r) * QKVD + col] = (bf16)(cv[r] * qs);
      } else if (n0 < 4096) {
        int kc = col - 2048;
#pragma unroll
        for (int r = 0; r < 4; ++r)
          Ko[(size_t)(row0 + r) * QKVD + kc] = (bf16)cv[r];
      } else {
        int vc = col - 4096;
#pragma unroll
        for (int r = 0; r < 4; ++r) {
          int tok = row0 + r; int bb = tok >> 11; int s = tok & 2047;
          Vto[((size_t)bb * QKVD + vc) * SEQ + s] = (bf16)cv[r];
        }
      }
    }
  }
}

// ---------------- Out-projection: 128x64 tile, grid 512 (2 blocks/CU), fp32 out ----------------
// out[4096,1024] = Ob[4096,2048] @ wo[1024,2048]^T. 4 waves: 2m x 2n, wave tile 64x32.
__global__ __launch_bounds__(256, 2) void proj_kernel(
    const bf16* __restrict__ A, const bf16* __restrict__ Bw, float* __restrict__ out)
{
  __shared__ bf16 PA[2][128 * 64];   // 16KB per buf
  __shared__ bf16 PB[2][64 * 64];    // 8KB per buf   (total 48KB -> 2 blocks/CU)

  const int tid  = threadIdx.x;
  const int lane = tid & 63;
  const int wid  = tid >> 6;     // 0..3
  const int wm   = wid >> 1;     // 0..1 (M half, 64 rows)
  const int wn   = wid & 1;      // 0..1 (N half, 32 cols)
  const int lm   = lane & 15;
  const int lg   = lane >> 4;

  // per-XCD chunk: 4 m-blocks x all 16 n (A slice 2MB + W 4.2MB ~ L2-resident)
  const int g   = blockIdx.x & 7;
  const int idx = blockIdx.x >> 3;            // 0..63
  const int m0  = (g * 4 + (idx >> 4)) * 128;
  const int n0  = (idx & 15) * 64;

  f32x4 acc[4][2];
#pragma unroll
  for (int i = 0; i < 4; ++i)
#pragma unroll
    for (int j = 0; j < 2; ++j) acc[i][j] = (f32x4)0.0f;

  auto stage = [&](int kt, int buf) {
    const int k0 = kt * 64;
    const int rl = lane >> 3;
    const int cb = (lane & 7) * 16;
#pragma unroll
    for (int i = 0; i < 4; ++i) {             // A: 16 chunks, 4/wave
      int chunk = wid * 4 + i;
      int row   = chunk * 8 + rl;
      int cx    = cb ^ ((row & 7) << 4);
      gload16(A + (size_t)(m0 + row) * QKVD + k0 + (cx >> 1), &PA[buf][chunk * 512]);
    }
#pragma unroll
    for (int i = 0; i < 2; ++i) {             // B: 8 chunks, 2/wave
      int chunk = wid * 2 + i;
      int row   = chunk * 8 + rl;
      int cx    = cb ^ ((row & 7) << 4);
      gload16(Bw + (size_t)(n0 + row) * QKVD + k0 + (cx >> 1), &PB[buf][chunk * 512]);
    }
  };

  stage(0, 0);

  for (int t = 0; t < 32; ++t) {
    const int c = t & 1;
    if (t < 31) {
      stage(t + 1, c ^ 1);
      asm volatile("s_waitcnt vmcnt(6)" ::: "memory");
    } else {
      asm volatile("s_waitcnt vmcnt(0)" ::: "memory");
    }
    __builtin_amdgcn_s_barrier();

    bf16x8 a[4][2], b[2][2];
#pragma unroll
    for (int mf = 0; mf < 4; ++mf)
#pragma unroll
      for (int kk = 0; kk < 2; ++kk) {
        int row = wm * 64 + mf * 16 + lm;
        int cb  = (kk * 64 + lg * 16) ^ ((row & 7) << 4);
        a[mf][kk] = *(const bf16x8*)((const char*)&PA[c][0] + row * 128 + cb);
      }
#pragma unroll
    for (int nf = 0; nf < 2; ++nf)
#pragma unroll
      for (int kk = 0; kk < 2; ++kk) {
        int row = wn * 32 + nf * 16 + lm;
        int cb  = (kk * 64 + lg * 16) ^ ((row & 7) << 4);
        b[nf][kk] = *(const bf16x8*)((const char*)&PB[c][0] + row * 128 + cb);
      }
    __builtin_amdgcn_s_barrier();
#pragma unroll
    for (int mf = 0; mf < 4; ++mf)
#pragma unroll
      for (int nf = 0; nf < 2; ++nf)
#pragma unroll
        for (int kk = 0; kk < 2; ++kk)
          acc[mf][nf] = __builtin_amdgcn_mfma_f32_16x16x32_bf16(a[mf][kk], b[nf][kk], acc[mf][nf], 0, 0, 0);
    __builtin_amdgcn_s_barrier();             // guards buf[c] reuse next iter
  }

#pragma unroll
  for (int mf = 0; mf < 4; ++mf)
#pragma unroll
    for (int nf = 0; nf < 2; ++nf) {
      int row0 = m0 + wm * 64 + mf * 16 + lg * 4;
      int col  = n0 + wn * 32 + nf * 16 + lm;
      f32x4 cv = acc[mf][nf];
#pragma unroll
      for (int r = 0; r < 4; ++r)
        out[(size_t)(row0 + r) * DMOD + col] = cv[r];
    }
}

// ---------------- Flash attention: swapped-QK^T 32x32, in-lane softmax ----------------
__global__ __launch_bounds__(256, 2) void flash_kernel(
    const bf16* __restrict__ Q, const bf16* __restrict__ Kg,
    const bf16* __restrict__ Vt, bf16* __restrict__ Po, float2* __restrict__ Pml)
{
  __shared__ bf16 KV[2][16384];      // per buf: K 64x128 (8192) | Vt 128x64 (8192) = 32KB

  const int tid  = threadIdx.x;
  const int lane = tid & 63;
  const int wid  = tid >> 6;
  const int l31  = lane & 31;
  const int lh   = lane >> 5;        // half: 0/1

  const int id   = blockIdx.x;               // 0..511
  const int bh   = (id & 7) * 4 + ((id >> 3) & 3);
  const int xx   = id >> 5;                  // 0..15
  const int pr   = xx >> 1;                  // pair index 0..7
  const int qpar = xx & 1;                   // parity 0/1
  const int b    = bh >> 4;
  const int h    = bh & 15;

  auto stage = [&](int j, int buf) {
    bf16* kb = &KV[buf][0];
    bf16* vb = &KV[buf][8192];
    const int rb0 = wid * 16;
#pragma unroll
    for (int i = 0; i < 4; ++i) {
      int r0 = rb0 + i * 4;
      int r  = r0 + (lane >> 4);
      int c  = ((lane & 15) * 16) ^ ((r & 7) << 4);
      gload16(Kg + ((size_t)(b * SEQ + j * 64 + r)) * QKVD + h * HDIM + (c >> 1),
              kb + r0 * 128);
    }
    const int db0 = wid * 32;
#pragma unroll
    for (int i = 0; i < 4; ++i) {
      int d0 = db0 + i * 8;
      int d  = d0 + (lane >> 3);
      int c  = ((lane & 7) * 16) ^ ((d & 7) << 4);
      gload16(Vt + ((size_t)(bh * HDIM + d)) * SEQ + j * 64 + (c >> 1),
              vb + d0 * 64);
    }
  };

  for (int sub = 0; sub < 2; ++sub) {
    const int T  = sub ? (15 - pr) : pr;     // tile index 0..15
    const int nu = T + 1;                    // units for this parity
    const int rA = T * 128 + wid * 32;       // wave's q-row base

    bf16x8 qfr[8];
    {
      const bf16* qb = Q + ((size_t)(b * SEQ + rA + l31)) * QKVD + h * HDIM + lh * 8;
#pragma unroll
      for (int st = 0; st < 8; ++st) qfr[st] = *reinterpret_cast<const bf16x8*>(qb + st * 16);
    }

    f32x16 o[4];
#pragma unroll
    for (int c = 0; c < 4; ++c) o[c] = (f32x16)0.0f;
    float mreg = -__builtin_inff();
    float lreg = 0.0f;

    stage(qpar, 0);
    __syncthreads();

    int cur = 0;
    for (int i = 0; i < nu; ++i) {
      const int j = qpar + 2 * i;            // kv-unit (64 keys)
      if (i + 1 < nu) stage(qpar + 2 * (i + 1), cur ^ 1);

      const bool act = (j * 64 <= rA + 31);
      if (act) {
        const char* kbb = (const char*)&KV[cur][0];
        const char* vbb = kbb + 16384;

        // ---- S^T = K Q^T ----
        f32x16 s0 = (f32x16)0.0f, s1 = (f32x16)0.0f;
#pragma unroll
        for (int st = 0; st < 8; ++st) {
          const int r0 = l31, r1 = 32 + l31;
          bf16x8 kf0 = *(const bf16x8*)(kbb + r0 * 256 + ((lh * 16 + st * 32) ^ ((r0 & 7) << 4)));
          bf16x8 kf1 = *(const bf16x8*)(kbb + r1 * 256 + ((lh * 16 + st * 32) ^ ((r1 & 7) << 4)));
          s0 = __builtin_amdgcn_mfma_f32_32x32x16_bf16(kf0, qfr[st], s0, 0, 0, 0);
          s1 = __builtin_amdgcn_mfma_f32_32x32x16_bf16(kf1, qfr[st], s1, 0, 0, 0);
        }

        // ---- causal mask ----
        const bool full = (j * 64 + 63) <= rA;
        if (!full) {
          const int qr  = rA + l31;
          const int kb0 = j * 64 + 4 * lh;
#pragma unroll
          for (int r = 0; r < 16; ++r) {
            int key = kb0 + (r & 3) + 8 * (r >> 2);
            if (key > qr)      s0[r] = -1e30f;
            if (key + 32 > qr) s1[r] = -1e30f;
          }
        }

        // ---- in-lane row stats ----
        float mx = s0[0];
#pragma unroll
        for (int r = 1; r < 16; ++r) mx = fmaxf(mx, s0[r]);
#pragma unroll
        for (int r = 0; r < 16; ++r) mx = fmaxf(mx, s1[r]);
        mx = fmaxf(mx, __shfl_xor(mx, 32));

        float mn;
        if (__all(mx <= mreg + 8.0f)) {
          mn = mreg;                          // defer-max
        } else {
          mn = fmaxf(mreg, mx);
          float scl = exp2f(mreg - mn);
          mreg = mn;
          lreg *= scl;
#pragma unroll
          for (int r = 0; r < 16; ++r) {
            int row = (r & 3) + 8 * (r >> 2) + 4 * lh;
            float sr = __shfl(scl, row);
#pragma unroll
            for (int c = 0; c < 4; ++c) o[c][r] *= sr;
          }
        }

        // ---- exp + sum ----
        float p[32];
#pragma unroll
        for (int r = 0; r < 16; ++r) p[r]      = exp2f(s0[r] - mn);
#pragma unroll
        for (int r = 0; r < 16; ++r) p[16 + r] = exp2f(s1[r] - mn);
        float rs = 0.0f;
#pragma unroll
        for (int r = 0; r < 32; ++r) rs += p[r];
        rs += __shfl_xor(rs, 32);
        lreg += rs;

        // ---- pack P into PV A-fragments ----
        bf16x8 pa[4];
#pragma unroll
        for (int f = 0; f < 4; ++f) {
          const float* pp = p + f * 8;
          uint32_t w0 = pkbf(pp[0], pp[1]);
          uint32_t w1 = pkbf(pp[2], pp[3]);
          uint32_t w2 = pkbf(pp[4], pp[5]);
          uint32_t w3 = pkbf(pp[6], pp[7]);
          plswap(w0, w2);
          plswap(w1, w3);
          u32x4 w = {w0, w1, w2, w3};
          pa[f] = __builtin_bit_cast(bf16x8, w);
        }

        // ---- O += P V ----
#pragma unroll
        for (int c = 0; c < 4; ++c) {
          const int d = c * 32 + l31;
          const char* vrow = vbb + d * 128;
          const int dx = (d & 7) << 4;
#pragma unroll
          for (int f = 0; f < 4; ++f) {
            bf16x8 vf = *(const bf16x8*)(vrow + ((f * 32 + lh * 16) ^ dx));
            o[c] = __builtin_amdgcn_mfma_f32_32x32x16_bf16(pa[f], vf, o[c], 0, 0, 0);
          }
        }
      }

      __syncthreads();
      cur ^= 1;
    }

    // ---- partial epilogue ----
    const int part = (bh * 16 + T) * 2 + qpar;
#pragma unroll
    for (int c = 0; c < 4; ++c)
#pragma unroll
      for (int r = 0; r < 16; ++r) {
        int row = (r & 3) + 8 * (r >> 2) + 4 * lh;
        Po[((size_t)part * 128 + wid * 32 + row) * 128 + c * 32 + l31] = (bf16)o[c][r];
      }
    if (lane < 32)
      Pml[part * 128 + wid * 32 + lane] = make_float2(mreg, lreg);
  }
}

// ---------------- merge the two parity partials per (bh, tile) ----------------
__global__ void merge_kernel(const bf16* __restrict__ Po, const float2* __restrict__ Pml,
                             bf16* __restrict__ Ob)
{
  const int id  = blockIdx.x;          // bh*16 + t
  const int bh  = id >> 4;
  const int t   = id & 15;
  const int tid = threadIdx.x;         // 256
  const int row = tid >> 1;
  const int dh  = (tid & 1) * 64;
  const int p0  = id * 2, p1 = id * 2 + 1;

  float2 ml0 = Pml[p0 * 128 + row];
  float2 ml1 = Pml[p1 * 128 + row];
  float M  = fmaxf(ml0.x, ml1.x);
  float w0 = exp2f(ml0.x - M);
  float w1 = exp2f(ml1.x - M);
  float inv = 1.0f / (ml0.y * w0 + ml1.y * w1);
  w0 *= inv; w1 *= inv;

  const bf16* o0 = Po + ((size_t)p0 * 128 + row) * 128 + dh;
  const bf16* o1 = Po + ((size_t)p1 * 128 + row) * 128 + dh;
  const int b = bh >> 4, h = bh & 15;
  bf16* out = Ob + ((size_t)(b * SEQ + t * 128 + row)) * QKVD + h * HDIM + dh;

#pragma unroll
  for (int v = 0; v < 8; ++v) {
    bf16x8 a = reinterpret_cast<const bf16x8*>(o0)[v];
    bf16x8 c = reinterpret_cast<const bf16x8*>(o1)[v];
    bf16x8 w;
#pragma unroll
    for (int k = 0; k < 8; ++k) w[k] = (bf16)((float)a[k] * w0 + (float)c[k] * w1);
    reinterpret_cast<bf16x8*>(out)[v] = w;
  }
}

// ---------------- launch ----------------
extern "C" void kernel_launch(void* const* d_in, const int* in_sizes, int n_in,
                              void* d_out, int out_size, void* d_ws, size_t ws_size,
                              hipStream_t stream) {
  const float* x  = (const float*)d_in[0];
  const float* wq = (const float*)d_in[1];
  const float* wk = (const float*)d_in[2];
  const float* wv = (const float*)d_in[3];
  const float* wo = (const float*)d_in[4];
  float* out = (float*)d_out;

  bf16* xb  = (bf16*)d_ws;                 // 4096x1024
  bf16* wqb = xb  + (size_t)NTOK * DMOD;   // 2048x1024 (wq/wk/wv contiguous = fused [6144,1024])
  bf16* wkb = wqb + (size_t)QKVD * DMOD;
  bf16* wvb = wkb + (size_t)QKVD * DMOD;
  bf16* wob = wvb + (size_t)QKVD * DMOD;   // 1024x2048
  bf16* Qb  = wob + (size_t)DMOD * QKVD;   // 4096x2048
  bf16* Kb  = Qb  + (size_t)NTOK * QKVD;
  bf16* Vtb = Kb  + (size_t)NTOK * QKVD;
  bf16* Ob  = Vtb + (size_t)NTOK * QKVD;
  bf16* Po  = Ob  + (size_t)NTOK * QKVD;   // 1024 x 128 x 128 bf16 partials
  float2* Pml = (float2*)(Po + (size_t)1024 * 128 * 128);  // 1024 x 128 float2

  // casts
  cast_f32_bf16<<<(NTOK * DMOD / 4) / 256, 256, 0, stream>>>(x,  xb,  NTOK * DMOD / 4);
  cast_f32_bf16<<<(QKVD * DMOD / 4) / 256, 256, 0, stream>>>(wq, wqb, QKVD * DMOD / 4);
  cast_f32_bf16<<<(QKVD * DMOD / 4) / 256, 256, 0, stream>>>(wk, wkb, QKVD * DMOD / 4);
  cast_f32_bf16<<<(QKVD * DMOD / 4) / 256, 256, 0, stream>>>(wv, wvb, QKVD * DMOD / 4);
  cast_f32_bf16<<<(DMOD * QKVD / 4) / 256, 256, 0, stream>>>(wo, wob, DMOD * QKVD / 4);

  // fused QKV projection: [4096,1024] @ [6144,1024]^T, grid 768 (3 exact rounds)
  const float qs = 0.08838834764831845f * 1.4426950408889634f;  // SCALE * log2(e)
  qkv_gemm_kernel<<<768, 512, 0, stream>>>(xb, wqb, Qb, Kb, Vtb, qs);

  // attention: 512 uniform blocks + merge
  flash_kernel<<<512, 256, 0, stream>>>(Qb, Kb, Vtb, Po, Pml);
  merge_kernel<<<512, 256, 0, stream>>>(Po, Pml, Ob);

  // output projection: [4096,2048] @ [1024,2048]^T -> [4096,1024] fp32, grid 512 (2/CU)
  proj_kernel<<<512, 256, 0, stream>>>(Ob, wob, out);
}